// Round 1
// baseline (1176.246 us; speedup 1.0000x reference)
//
#include <hip/hip_runtime.h>
#include <hip/hip_bf16.h>
#include <math.h>

// Problem constants
#define NB   1024   // batch
#define NT   60     // time steps
#define NC   10     // in channels
#define NDM  256    // d_model
#define NH   16     // heads
#define NDH  16     // per-head dim
#define NA   13     // num attention queries
#define NDK  4      // d_k
#define NM   208    // NA*NH
#define NMO  128    // MLP out

// Workspace layout (floats)
#define OFF_VG    0
#define N_VG      (NB*NT*NDM)                  // 15,728,640
#define OFF_WEFF  (OFF_VG + N_VG)
#define N_WEFF    (NM*NH*NDM*NA)               // 11,075,584
#define OFF_BEFF  (OFF_WEFF + N_WEFF)
#define N_BEFF    (NM*NH*NA)                   // 43,264
#define OFF_ATT   (OFF_BEFF + N_BEFF)
#define N_ATT     (NM*NB*NDH)                  // 3,407,872

// ---------------- K0: weff[m][hk][d][ak] = sum_dk Q[m,dk]*Wk[(ak*16+hk)*4+dk, d]
__global__ void ltae_weff(const float* __restrict__ Q, const float* __restrict__ Wk,
                          const float* __restrict__ bk, float* __restrict__ weff2,
                          float* __restrict__ beff2) {
    int blk = blockIdx.x;            // m*16 + hk
    int m = blk >> 4, hk = blk & 15;
    int d = threadIdx.x;
    float q0 = Q[m*4+0], q1 = Q[m*4+1], q2 = Q[m*4+2], q3 = Q[m*4+3];
    float outv[NA];
#pragma unroll
    for (int ak = 0; ak < NA; ++ak) {
        int e = (ak*16 + hk)*4;
        outv[ak] = q0*Wk[(size_t)(e+0)*NDM + d] + q1*Wk[(size_t)(e+1)*NDM + d]
                 + q2*Wk[(size_t)(e+2)*NDM + d] + q3*Wk[(size_t)(e+3)*NDM + d];
    }
    size_t base = ((size_t)blk*NDM + d)*NA;
#pragma unroll
    for (int ak = 0; ak < NA; ++ak) weff2[base + ak] = outv[ak];
    if (d < NA) {
        int e = (d*16 + hk)*4;
        beff2[blk*NA + d] = q0*bk[e] + q1*bk[e+1] + q2*bk[e+2] + q3*bk[e+3];
    }
}

// ---------------- K1: 1x1 conv + GroupNorm(16 groups over [16ch x 60t]) -> v[b][t][d]
__global__ void ltae_convgn(const float* __restrict__ x, const float* __restrict__ Wc,
                            const float* __restrict__ bc, const float* __restrict__ gnw,
                            const float* __restrict__ gnb, float* __restrict__ vg) {
    __shared__ float xl[NT*NC];
    int b = blockIdx.x, tid = threadIdx.x;
    for (int i = tid; i < NT*NC; i += 256) xl[i] = x[(size_t)b*NT*NC + i];
    __syncthreads();
    float wc[NC];
#pragma unroll
    for (int c = 0; c < NC; ++c) wc[c] = Wc[tid*NC + c];
    float bcv = bc[tid];
    float h[NT];
    float s1 = 0.f, s2 = 0.f;
    for (int t = 0; t < NT; ++t) {
        float a = bcv;
#pragma unroll
        for (int c = 0; c < NC; ++c) a += xl[t*NC + c]*wc[c];
        h[t] = a; s1 += a; s2 += a*a;
    }
#pragma unroll
    for (int off = 1; off < 16; off <<= 1) {
        s1 += __shfl_xor(s1, off);
        s2 += __shfl_xor(s2, off);
    }
    float mean = s1 * (1.f/960.f);
    float var  = s2 * (1.f/960.f) - mean*mean;
    float rstd = rsqrtf(var + 1e-5f);
    float g = gnw[tid], bb = gnb[tid];
    for (int t = 0; t < NT; ++t)
        vg[((size_t)b*NT + t)*NDM + tid] = (h[t]-mean)*rstd*g + bb;
}

// ---------------- K2: scrambled attention per batch sample b
#define VT_S   68
#define VT_W   (NDM*VT_S)          // 17408 words
#define W_HS   36
#define W_DS   (NH*W_HS)           // 576 words per dd
#define WC_W   (32*W_DS)           // 18432 words
#define C_TS   14
#define C_HS   (64*C_TS)           // 896
#define ATT_W  (4*64)
#define K2_LDS_BYTES ((VT_W + WC_W + ATT_W) * 4)   // 144,384

__launch_bounds__(256, 1)
__global__ void ltae_attn(const float* __restrict__ vg, const float* __restrict__ weff2,
                          const float* __restrict__ beff2, float* __restrict__ attout) {
    extern __shared__ float smem[];
    float* Vt    = smem;
    float* WC    = smem + VT_W;
    float* attns = smem + VT_W + WC_W;

    int b   = blockIdx.x;
    int tid = threadIdx.x;
    int hk  = tid >> 4;
    int tkt = tid & 15;
    int tk0 = tkt * 4;

    // load v[b] transposed into LDS: Vt[d][t]
    for (int i = tid; i < NT*(NDM/4); i += 256) {
        int t  = i >> 6;
        int d4 = (i & 63) * 4;
        float4 vv = *(const float4*)&vg[((size_t)b*NT + t)*NDM + d4];
        Vt[(d4+0)*VT_S + t] = vv.x;
        Vt[(d4+1)*VT_S + t] = vv.y;
        Vt[(d4+2)*VT_S + t] = vv.z;
        Vt[(d4+3)*VT_S + t] = vv.w;
    }
    for (int i = tid; i < NDM*8; i += 256) {
        int d = i >> 3, t = NT + (i & 7);
        Vt[d*VT_S + t] = 0.f;
    }

    int hb13  = hk*1024 + b;
    int n13   = hb13 * 13;
    int m0    = n13 >> 10;
    int rstar = ((m0+1) << 10) - n13;
    int vb[4];
#pragma unroll
    for (int i = 0; i < 4; ++i) {
        int tkc = tk0 + i; if (tkc > 59) tkc = 59;
        vb[i] = (13*tkc >= 60*rstar) ? 16 : 0;
    }
    bool uni = (vb[0] == vb[3]);

    float acc[4][NA];
#pragma unroll
    for (int i = 0; i < 4; ++i)
#pragma unroll
        for (int j = 0; j < NA; ++j) acc[i][j] = 0.f;

    __syncthreads();

    for (int dc = 0; dc < 8; ++dc) {
        for (int flat = tid; flat < 13312; flat += 256) {
            int rest = flat / 13;
            int ak   = flat - rest*13;
            int dd   = rest & 31;
            int rest2 = rest >> 5;
            int var  = rest2 & 1;
            int hkl  = rest2 >> 1;
            int n13l = (hkl*1024 + b)*13;
            int m0l  = n13l >> 10;
            bool nB  = ((((m0l+1) << 10) - n13l) < 13);
            if (var == 0 || nB) {
                int mld = m0l + var;
                WC[dd*W_DS + hkl*W_HS + var*16 + ak] =
                    weff2[(((size_t)(mld*16 + hkl))*NDM + (dc*32 + dd))*NA + ak];
            }
        }
        __syncthreads();
        for (int dd = 0; dd < 32; ++dd) {
            int d = dc*32 + dd;
            float4 v4 = *(const float4*)&Vt[d*VT_S + tk0];
            float vv[4] = {v4.x, v4.y, v4.z, v4.w};
            const float* wr = &WC[dd*W_DS + hk*W_HS];
            if (uni) {
                const float* w = wr + vb[0];
#pragma unroll
                for (int i = 0; i < 4; ++i)
#pragma unroll
                    for (int j = 0; j < NA; ++j)
                        acc[i][j] = fmaf(vv[i], w[j], acc[i][j]);
            } else {
#pragma unroll
                for (int i = 0; i < 4; ++i) {
                    const float* w = wr + vb[i];
#pragma unroll
                    for (int j = 0; j < NA; ++j)
                        acc[i][j] = fmaf(vv[i], w[j], acc[i][j]);
                }
            }
        }
        __syncthreads();
    }

#pragma unroll
    for (int i = 0; i < 4; ++i)
#pragma unroll
        for (int j = 0; j < NA; ++j)
            WC[hk*C_HS + (tk0+i)*C_TS + j] = acc[i][j];
    __syncthreads();

    int wave = tid >> 6, lane = tid & 63;
    for (int task = wave; task < NH*NA; task += 4) {
        int hkt = task / NA;
        int r   = task - hkt*NA;
        int hb  = hkt*1024 + b;
        int nn  = hb*13 + r;
        int m0t = (hb*13) >> 10;
        int rst = ((m0t+1) << 10) - hb*13;
        int m   = nn >> 10;
        float logit = -3.4e38f;
        if (lane < NT) {
            int u   = r*60 + lane;
            int tkl = u / 13;
            int akl = u - tkl*13;
            float cv = WC[hkt*C_HS + tkl*C_TS + akl];
            int vbu  = (13*tkl >= 60*rst) ? 1 : 0;
            if (m0t + vbu != m) {
                float s = 0.f;
                const float* wrow = &weff2[((size_t)(m*16 + hkt)*NDM)*NA + akl];
                for (int d = 0; d < NDM; ++d)
                    s += wrow[(size_t)d*NA] * Vt[d*VT_S + tkl];
                cv = s;
            }
            logit = (cv + beff2[(m*16 + hkt)*NA + akl]) * 0.5f;
        }
        float mx = logit;
#pragma unroll
        for (int off = 32; off; off >>= 1) mx = fmaxf(mx, __shfl_xor(mx, off));
        float e = (lane < NT) ? __expf(logit - mx) : 0.f;
        float s = e;
#pragma unroll
        for (int off = 32; off; off >>= 1) s += __shfl_xor(s, off);
        float attn = e / s;
        attns[wave*64 + lane] = attn;
        __asm__ __volatile__("s_waitcnt lgkmcnt(0)" ::: "memory");
        int dh = lane >> 2, cc = lane & 3;
        const float* vrow = &Vt[(hkt*16 + dh)*VT_S];
        float a = 0.f;
#pragma unroll
        for (int j = 0; j < 15; ++j) {
            int t = cc + 4*j;
            a += attns[wave*64 + t] * vrow[t];
        }
        a += __shfl_xor(a, 1);
        a += __shfl_xor(a, 2);
        if (cc == 0) attout[(size_t)nn*NDH + dh] = a;
    }
}

// ---------------- K3: MLP + BN(eval) + ReLU + GroupNorm(16,128) -> out[b][a][128]
__global__ void ltae_mlp(const float* __restrict__ attout, const float* __restrict__ W1,
                         const float* __restrict__ b1, const float* __restrict__ bnw,
                         const float* __restrict__ bnb, const float* __restrict__ bnrm,
                         const float* __restrict__ bnrv, const float* __restrict__ gow,
                         const float* __restrict__ gob, float* __restrict__ out) {
    __shared__ float f[2][NDM];
    int tid  = threadIdx.x;
    int half = tid >> 7;
    int j    = tid & 127;
    int sid  = (blockIdx.x << 1) + half;     // sid = a2*1024 + b2
    int a2   = sid >> 10, b2 = sid & 1023;
    for (int c = j; c < NDM; c += 128) {
        int h2 = c >> 4, dh = c & 15;
        int nn = (a2*16 + h2)*1024 + b2;
        f[half][c] = attout[(size_t)nn*NDH + dh];
    }
    __syncthreads();
    const float* fr = f[half];
    const float* w  = &W1[(size_t)j*NDM];
    float acc = b1[j];
    for (int c = 0; c < NDM; c += 4) {
        float4 wv = *(const float4*)&w[c];
        acc += wv.x*fr[c] + wv.y*fr[c+1] + wv.z*fr[c+2] + wv.w*fr[c+3];
    }
    float y = (acc - bnrm[j]) * rsqrtf(bnrv[j] + 1e-5f) * bnw[j] + bnb[j];
    y = fmaxf(y, 0.f);
    float s1 = y, s2 = y*y;
#pragma unroll
    for (int off = 1; off < 8; off <<= 1) {
        s1 += __shfl_xor(s1, off);
        s2 += __shfl_xor(s2, off);
    }
    float mean = s1 * 0.125f;
    float var  = s2 * 0.125f - mean*mean;
    float o = (y - mean) * rsqrtf(var + 1e-5f) * gow[j] + gob[j];
    out[((size_t)b2*NA + a2)*NMO + j] = o;
}

extern "C" void kernel_launch(void* const* d_in, const int* in_sizes, int n_in,
                              void* d_out, int out_size, void* d_ws, size_t ws_size,
                              hipStream_t stream) {
    const float* x    = (const float*)d_in[0];
    const float* Wc   = (const float*)d_in[1];
    const float* bc   = (const float*)d_in[2];
    const float* gnw  = (const float*)d_in[3];
    const float* gnb  = (const float*)d_in[4];
    const float* Q    = (const float*)d_in[5];
    const float* Wk   = (const float*)d_in[6];
    const float* bk   = (const float*)d_in[7];
    const float* W1   = (const float*)d_in[8];
    const float* b1   = (const float*)d_in[9];
    const float* bnw  = (const float*)d_in[10];
    const float* bnb  = (const float*)d_in[11];
    const float* bnrm = (const float*)d_in[12];
    const float* bnrv = (const float*)d_in[13];
    const float* gow  = (const float*)d_in[14];
    const float* gob  = (const float*)d_in[15];

    float* ws     = (float*)d_ws;
    float* vg     = ws + OFF_VG;
    float* weff2  = ws + OFF_WEFF;
    float* beff2  = ws + OFF_BEFF;
    float* attout = ws + OFF_ATT;
    float* outp   = (float*)d_out;

    hipLaunchKernelGGL(ltae_weff, dim3(NM*NH), dim3(256), 0, stream, Q, Wk, bk, weff2, beff2);
    hipLaunchKernelGGL(ltae_convgn, dim3(NB), dim3(256), 0, stream, x, Wc, bc, gnw, gnb, vg);
    hipFuncSetAttribute((const void*)ltae_attn,
                        hipFuncAttributeMaxDynamicSharedMemorySize, K2_LDS_BYTES);
    hipLaunchKernelGGL(ltae_attn, dim3(NB), dim3(256), K2_LDS_BYTES, stream,
                       vg, weff2, beff2, attout);
    hipLaunchKernelGGL(ltae_mlp, dim3(NA*NB/2), dim3(256), 0, stream,
                       attout, W1, b1, bnw, bnb, bnrm, bnrv, gow, gob, outp);
}

// Round 3
// 541.143 us; speedup vs baseline: 2.1736x; 2.1736x over previous
//
#include <hip/hip_runtime.h>
#include <hip/hip_bf16.h>
#include <math.h>

// Problem constants
#define NB   1024   // batch
#define NT   60     // time steps
#define NC   10     // in channels
#define NDM  256    // d_model
#define NH   16     // heads
#define NDH  16     // per-head value dim
#define NA   13     // num attention queries
#define NM   208    // NA*NH
#define NMO  128    // MLP out

// Workspace layout (floats)
#define OFF_WEFF  0
#define N_WEFF    (NM*NH*NDM*NA)               // 11,075,584
#define OFF_BEFF  (OFF_WEFF + N_WEFF)
#define N_BEFF    (NM*NH*NA)                   // 43,264
#define OFF_ATT   (OFF_BEFF + N_BEFF)
#define N_ATT     (NM*NB*NDH)                  // 3,407,872

// ---------------- K0: weff[m][hk][d][ak] = sum_dk Q[m,dk]*Wk[(ak*16+hk)*4+dk, d]
__global__ void ltae_weff(const float* __restrict__ Q, const float* __restrict__ Wk,
                          const float* __restrict__ bk, float* __restrict__ weff2,
                          float* __restrict__ beff2) {
    int blk = blockIdx.x;            // m*16 + hk
    int m = blk >> 4, hk = blk & 15;
    int d = threadIdx.x;
    float q0 = Q[m*4+0], q1 = Q[m*4+1], q2 = Q[m*4+2], q3 = Q[m*4+3];
    float outv[NA];
#pragma unroll
    for (int ak = 0; ak < NA; ++ak) {
        int e = (ak*16 + hk)*4;
        outv[ak] = q0*Wk[(size_t)(e+0)*NDM + d] + q1*Wk[(size_t)(e+1)*NDM + d]
                 + q2*Wk[(size_t)(e+2)*NDM + d] + q3*Wk[(size_t)(e+3)*NDM + d];
    }
    size_t base = ((size_t)blk*NDM + d)*NA;
#pragma unroll
    for (int ak = 0; ak < NA; ++ak) weff2[base + ak] = outv[ak];
    if (d < NA) {
        int e = (d*16 + hk)*4;
        beff2[blk*NA + d] = q0*bk[e] + q1*bk[e+1] + q2*bk[e+2] + q3*bk[e+3];
    }
}

// ---------------- K2: fused conv+GN + scrambled attention; block = b, wave = hk
// LDS: Vt fp32 [256][68] + C fp32 [16 waves][784]
#define VT_S   68
#define VT_F   (NDM*VT_S)            // 17,408 floats
#define C_F    (NH*784)              // 12,544 floats
#define K2_LDS_BYTES ((VT_F + C_F)*4)  // 119,808 B -> 1 block/CU, 16 waves

__launch_bounds__(1024, 4)
__global__ void ltae_fused(const float* __restrict__ x, const float* __restrict__ Wc,
                           const float* __restrict__ bc, const float* __restrict__ gnw,
                           const float* __restrict__ gnb, const float* __restrict__ weff2,
                           const float* __restrict__ beff2, float* __restrict__ attout) {
    extern __shared__ float smem[];
    float* Vt = smem;
    float* Cb = smem + VT_F;

    int b = blockIdx.x, tid = threadIdx.x;

    // ---- stage x[b] (600 floats) into C region (dead until GEMM dump)
    float* xs = Cb;
    if (tid < NT*NC) xs[tid] = x[(size_t)b*NT*NC + tid];
    __syncthreads();

    // ---- conv 1x1 + GroupNorm(16 groups over 16ch x 60t), write Vt fp32 [d][t]
    {
        int d = tid >> 2, q = tid & 3;   // wave w covers d in [16w,16w+16) = GN group w
        float wc[NC];
#pragma unroll
        for (int c = 0; c < NC; ++c) wc[c] = Wc[d*NC + c];
        float bcv = bc[d];
        float h[15];
        float s1 = 0.f, s2 = 0.f;
#pragma unroll
        for (int k = 0; k < 15; ++k) {
            int t = 15*q + k;
            float a = bcv;
#pragma unroll
            for (int c = 0; c < NC; ++c) a = fmaf(xs[t*NC + c], wc[c], a);
            h[k] = a; s1 += a; s2 += a*a;
        }
#pragma unroll
        for (int off = 1; off < 64; off <<= 1) {
            s1 += __shfl_xor(s1, off);
            s2 += __shfl_xor(s2, off);
        }
        float mean = s1 * (1.f/960.f);
        float var  = s2 * (1.f/960.f) - mean*mean;
        float rstd = rsqrtf(var + 1e-5f);
        float g = gnw[d], bb = gnb[d];
#pragma unroll
        for (int k = 0; k < 15; ++k) {
            int t = 15*q + k;
            Vt[d*VT_S + t] = (h[k]-mean)*rstd*g + bb;
        }
        if (q == 0) {
#pragma unroll
            for (int t = NT; t < VT_S; ++t) Vt[d*VT_S + t] = 0.f;
        }
    }
    __syncthreads();

    // ---- per-wave attention: wave = hk, lane = tk
    int wid = tid >> 6, lane = tid & 63;
    int hk = __builtin_amdgcn_readfirstlane(wid);   // force SGPR -> uniform weight ptr
    int tk = lane;
    int hb13  = (hk*1024 + b)*13;
    int m0    = hb13 >> 10;
    int rstar = ((m0+1) << 10) - hb13;              // 1..1024; variant switch if <13

    float acc[13];
#pragma unroll
    for (int j = 0; j < 13; ++j) acc[j] = 0.f;

    // pass A: weight row m0 (wave-uniform -> scalar-load path)
    {
        const float4* __restrict__ wr = (const float4*)(weff2 + ((size_t)(m0*16 + hk))*NDM*NA);
        for (int d4 = 0; d4 < 64; ++d4) {
            float4 w[13];
#pragma unroll
            for (int i = 0; i < 13; ++i) w[i] = wr[d4*13 + i];
            float v[4];
#pragma unroll
            for (int dd = 0; dd < 4; ++dd) v[dd] = Vt[(4*d4+dd)*VT_S + tk];
#pragma unroll
            for (int dd = 0; dd < 4; ++dd)
#pragma unroll
                for (int ak = 0; ak < 13; ++ak) {
                    int e = dd*13 + ak;
                    float we = ((const float*)w)[e];
                    acc[ak] = fmaf(v[dd], we, acc[ak]);
                }
        }
    }
    // pass B (rare boundary waves): weight row m0+1, exact per-(tk,ak) select
    if (rstar < 13) {
        float accB[13];
#pragma unroll
        for (int j = 0; j < 13; ++j) accB[j] = 0.f;
        const float4* __restrict__ wr = (const float4*)(weff2 + ((size_t)((m0+1)*16 + hk))*NDM*NA);
        for (int d4 = 0; d4 < 64; ++d4) {
            float4 w[13];
#pragma unroll
            for (int i = 0; i < 13; ++i) w[i] = wr[d4*13 + i];
            float v[4];
#pragma unroll
            for (int dd = 0; dd < 4; ++dd) v[dd] = Vt[(4*d4+dd)*VT_S + tk];
#pragma unroll
            for (int dd = 0; dd < 4; ++dd)
#pragma unroll
                for (int ak = 0; ak < 13; ++ak) {
                    int e = dd*13 + ak;
                    float we = ((const float*)w)[e];
                    accB[ak] = fmaf(v[dd], we, accB[ak]);
                }
        }
#pragma unroll
        for (int j = 0; j < 13; ++j)
            if (13*tk + j >= 60*rstar) acc[j] = accB[j];
    }

    // ---- dump C in u-layout (u = 13*tk + ak); wave-private row, no block barrier
    float* Crow = Cb + hk*784;
    if (tk < NT) {
#pragma unroll
        for (int j = 0; j < 13; ++j) Crow[13*tk + j] = acc[j];
    }
    __asm__ __volatile__("s_waitcnt lgkmcnt(0)" ::: "memory");

    // ---- softmax + AV per r (13 rows), all within this wave, fp32 throughout
    int dh = lane >> 2, cc = lane & 3;
    const float* vrow = Vt + (hk*16 + dh)*VT_S;
    for (int r = 0; r < 13; ++r) {
        int n = hb13 + r;
        int m = n >> 10;                             // exact weight/bias variant for this row
        int brow = (m*16 + hk)*13;
        float logit = -1e30f;
        if (lane < NT) {
            int u  = r*60 + lane;
            int ak = u % 13;
            logit = (Crow[u] + beff2[brow + ak]) * 0.5f;
        }
        float mx = logit;
#pragma unroll
        for (int off = 32; off; off >>= 1) mx = fmaxf(mx, __shfl_xor(mx, off));
        float e = (lane < NT) ? __expf(logit - mx) : 0.f;
        float s = e;
#pragma unroll
        for (int off = 32; off; off >>= 1) s += __shfl_xor(s, off);
        float attn = e / s;
        // store attn in-place over the already-consumed C row (same-wave, in-order LDS)
        if (lane < NT) Crow[r*60 + lane] = attn;
        __asm__ __volatile__("s_waitcnt lgkmcnt(0)" ::: "memory");
        // AV: lane = dh*4+cc; t = cc+4j covers 0..59 exactly
        float a = 0.f;
#pragma unroll
        for (int j = 0; j < 15; ++j) {
            int t = cc + 4*j;
            a = fmaf(Crow[r*60 + t], vrow[t], a);
        }
        a += __shfl_xor(a, 1);
        a += __shfl_xor(a, 2);
        if (cc == 0) attout[(size_t)n*NDH + dh] = a;
    }
}

// ---------------- K3: MLP + BN(eval) + ReLU + GroupNorm(16,128) -> out[b][a][128]
__global__ void ltae_mlp(const float* __restrict__ attout, const float* __restrict__ W1,
                         const float* __restrict__ b1, const float* __restrict__ bnw,
                         const float* __restrict__ bnb, const float* __restrict__ bnrm,
                         const float* __restrict__ bnrv, const float* __restrict__ gow,
                         const float* __restrict__ gob, float* __restrict__ out) {
    __shared__ float f[2][NDM];
    int tid  = threadIdx.x;
    int half = tid >> 7;
    int j    = tid & 127;
    int sid  = (blockIdx.x << 1) + half;     // sid = a2*1024 + b2
    int a2   = sid >> 10, b2 = sid & 1023;
    for (int c = j; c < NDM; c += 128) {
        int h2 = c >> 4, dhh = c & 15;
        int nn = (a2*16 + h2)*1024 + b2;
        f[half][c] = attout[(size_t)nn*NDH + dhh];
    }
    __syncthreads();
    const float* fr = f[half];
    const float* w  = &W1[(size_t)j*NDM];
    float acc = b1[j];
    for (int c = 0; c < NDM; c += 4) {
        float4 wv = *(const float4*)&w[c];
        acc += wv.x*fr[c] + wv.y*fr[c+1] + wv.z*fr[c+2] + wv.w*fr[c+3];
    }
    float y = (acc - bnrm[j]) * rsqrtf(bnrv[j] + 1e-5f) * bnw[j] + bnb[j];
    y = fmaxf(y, 0.f);
    float s1 = y, s2 = y*y;
#pragma unroll
    for (int off = 1; off < 8; off <<= 1) {
        s1 += __shfl_xor(s1, off);
        s2 += __shfl_xor(s2, off);
    }
    float mean = s1 * 0.125f;
    float var  = s2 * 0.125f - mean*mean;
    float o = (y - mean) * rsqrtf(var + 1e-5f) * gow[j] + gob[j];
    out[((size_t)b2*NA + a2)*NMO + j] = o;
}

extern "C" void kernel_launch(void* const* d_in, const int* in_sizes, int n_in,
                              void* d_out, int out_size, void* d_ws, size_t ws_size,
                              hipStream_t stream) {
    const float* x    = (const float*)d_in[0];
    const float* Wc   = (const float*)d_in[1];
    const float* bc   = (const float*)d_in[2];
    const float* gnw  = (const float*)d_in[3];
    const float* gnb  = (const float*)d_in[4];
    const float* Q    = (const float*)d_in[5];
    const float* Wk   = (const float*)d_in[6];
    const float* bk   = (const float*)d_in[7];
    const float* W1   = (const float*)d_in[8];
    const float* b1   = (const float*)d_in[9];
    const float* bnw  = (const float*)d_in[10];
    const float* bnb  = (const float*)d_in[11];
    const float* bnrm = (const float*)d_in[12];
    const float* bnrv = (const float*)d_in[13];
    const float* gow  = (const float*)d_in[14];
    const float* gob  = (const float*)d_in[15];

    float* ws     = (float*)d_ws;
    float* weff2  = ws + OFF_WEFF;
    float* beff2  = ws + OFF_BEFF;
    float* attout = ws + OFF_ATT;
    float* outp   = (float*)d_out;

    hipLaunchKernelGGL(ltae_weff, dim3(NM*NH), dim3(256), 0, stream, Q, Wk, bk, weff2, beff2);
    hipFuncSetAttribute((const void*)ltae_fused,
                        hipFuncAttributeMaxDynamicSharedMemorySize, K2_LDS_BYTES);
    hipLaunchKernelGGL(ltae_fused, dim3(NB), dim3(1024), K2_LDS_BYTES, stream,
                       x, Wc, bc, gnw, gnb, weff2, beff2, attout);
    hipLaunchKernelGGL(ltae_mlp, dim3(NA*NB/2), dim3(256), 0, stream,
                       attout, W1, b1, bnw, bnb, bnrm, bnrv, gow, gob, outp);
}